// Round 3
// baseline (158.281 us; speedup 1.0000x reference)
//
#include <hip/hip_runtime.h>

constexpr int L = 12;
constexpr int B = 4, T = 2048, H = 16, D = 64;
constexpr int NPOS = B * T * H;                     // 131072 positions (b,t,h)
constexpr long long SLAYER = (long long)NPOS * D;   // elements per layer slice
constexpr int PITER = 4;                            // 4-position iters per wave

// Mt[c][d] = M[d][c] = sum_e Wq[e][d] * Wk[e][c]   (score_l = x^T M y_l)
__global__ __launch_bounds__(64) void cla_precompute_Mt(
    const float* __restrict__ Wq, const float* __restrict__ Wk,
    float* __restrict__ Mt) {
  const int d = blockIdx.x;    // 64 blocks
  const int c = threadIdx.x;   // 64 threads
  float acc = 0.f;
  #pragma unroll
  for (int e = 0; e < D; ++e)
    acc = fmaf(Wq[e * D + d], Wk[e * D + c], acc);
  Mt[c * D + d] = acc;
}

// Sum over each 16-lane row via DPP row_ror (VALU pipe, no LDS ops).
// After 4 rotate-accumulate steps every lane holds its row's full sum.
template <int CTRL>
__device__ __forceinline__ float ror_add(float x) {
  int moved = __builtin_amdgcn_update_dpp(0, __float_as_int(x), CTRL, 0xF, 0xF,
                                          false);
  return x + __int_as_float(moved);
}
__device__ __forceinline__ float row_sum16(float x) {
  x = ror_add<0x121>(x);  // row_ror:1
  x = ror_add<0x122>(x);  // row_ror:2
  x = ror_add<0x124>(x);  // row_ror:4
  x = ror_add<0x128>(x);  // row_ror:8
  return x;
}

__global__ __launch_bounds__(256) void cla_main(
    const float* __restrict__ cur, const float* __restrict__ all,
    const float* __restrict__ Mt, const float* __restrict__ scales,
    const float* __restrict__ temperature, float* __restrict__ out) {
  __shared__ float vlds[4][4 * D];   // per-wave v-transpose scratch (4 KB)

  const int lane = threadIdx.x & 63;
  const int w    = __builtin_amdgcn_readfirstlane(threadIdx.x >> 6);
  const int wid  = blockIdx.x * 4 + w;   // uniform

  // Lane's M column: Mc[d] = M[d][lane], loaded once per wave (L2-hot 16 KB).
  float Mc[D];
  {
    const float4* mt = (const float4*)(Mt + lane * D);
    #pragma unroll
    for (int c = 0; c < 16; ++c) {
      const float4 m = mt[c];
      Mc[4 * c + 0] = m.x;
      Mc[4 * c + 1] = m.y;
      Mc[4 * c + 2] = m.z;
      Mc[4 * c + 3] = m.w;
    }
  }

  const float inv_scale = 1.0f / (8.0f * fabsf(temperature[0]));  // sqrt(64)=8
  float scl[L];
  #pragma unroll
  for (int l = 0; l < L; ++l) scl[l] = scales[l];

  const int g = lane >> 4;   // position group within wave
  const int j = lane & 15;   // chunk lane within group

  for (int t = 0; t < PITER; ++t) {
    const int pos0 = (wid * PITER + t) * 4;       // uniform
    const size_t base = (size_t)pos0 * D;         // 4 positions = 256 floats

    // Phase 1: v = M^T x per position; x address wave-uniform (same-line
    // loads / scalarizable). v[c] accumulates in lane c.
    #pragma unroll
    for (int p = 0; p < 4; ++p) {
      const float4* xp = (const float4*)(cur + base + (size_t)p * D);
      float v = 0.f;
      #pragma unroll
      for (int c4 = 0; c4 < 16; ++c4) {
        const float4 xv = xp[c4];
        v = fmaf(xv.x, Mc[4 * c4 + 0], v);
        v = fmaf(xv.y, Mc[4 * c4 + 1], v);
        v = fmaf(xv.z, Mc[4 * c4 + 2], v);
        v = fmaf(xv.w, Mc[4 * c4 + 3], v);
      }
      vlds[w][p * D + lane] = v;   // ds_write_b32, conflict-free
    }

    // Phase 2: register transpose (same-wave LDS, no barrier needed):
    // lane picks up q chunk = v_{pos g}[4j..4j+3].
    const float4 q = *(const float4*)&vlds[w][g * D + 4 * j];

    // Phase 3: single pass over all_layers; 1 KB coalesced per layer.
    float4 y[L];
    #pragma unroll
    for (int l = 0; l < L; ++l)
      y[l] = ((const float4*)(all + (size_t)l * SLAYER + base))[lane];

    // Scores: per-lane partial dot + DPP 16-lane row reduce (all-VALU).
    float sc[L];
    #pragma unroll
    for (int l = 0; l < L; ++l) {
      float s = q.x * y[l].x + q.y * y[l].y + q.z * y[l].z + q.w * y[l].w;
      sc[l] = row_sum16(s) * inv_scale;
    }

    // Softmax over L (redundant per lane; values uniform within the group).
    float mx = sc[0];
    #pragma unroll
    for (int l = 1; l < L; ++l) mx = fmaxf(mx, sc[l]);
    float sum = 0.f;
    #pragma unroll
    for (int l = 0; l < L; ++l) { sc[l] = __expf(sc[l] - mx); sum += sc[l]; }
    const float inv_sum = 1.0f / sum;

    float wgt[L];
    float ssum = 0.f;
    #pragma unroll
    for (int l = 0; l < L; ++l) {
      wgt[l] = sc[l] * inv_sum * scl[l];
      ssum += wgt[l];
    }
    const float r = 1.0f / (ssum + 1e-6f);

    float o0 = 0.f, o1 = 0.f, o2 = 0.f, o3 = 0.f;
    #pragma unroll
    for (int l = 0; l < L; ++l) {
      const float wl = wgt[l] * r * scl[l];
      o0 = fmaf(wl, y[l].x, o0);
      o1 = fmaf(wl, y[l].y, o1);
      o2 = fmaf(wl, y[l].z, o2);
      o3 = fmaf(wl, y[l].w, o3);
    }
    ((float4*)(out + base))[lane] = make_float4(o0, o1, o2, o3);
  }
}

extern "C" void kernel_launch(void* const* d_in, const int* in_sizes, int n_in,
                              void* d_out, int out_size, void* d_ws, size_t ws_size,
                              hipStream_t stream) {
  const float* cur    = (const float*)d_in[0];
  const float* all    = (const float*)d_in[1];
  const float* Wq     = (const float*)d_in[2];
  const float* Wk     = (const float*)d_in[3];
  const float* scales = (const float*)d_in[4];
  const float* temp   = (const float*)d_in[5];
  float* Mt = (float*)d_ws;   // 16 KB scratch: (Wq^T Wk)^T

  cla_precompute_Mt<<<64, 64, 0, stream>>>(Wq, Wk, Mt);

  // 131072 positions / (4 per iter * PITER per wave) = 8192 waves = 2048 blocks
  const int nblocks = NPOS / (4 * PITER * 4);
  cla_main<<<nblocks, 256, 0, stream>>>(cur, all, Mt, scales, temp,
                                        (float*)d_out);
}

// Round 4
// 105.593 us; speedup vs baseline: 1.4990x; 1.4990x over previous
//
#include <hip/hip_runtime.h>
#include <hip/hip_bf16.h>

constexpr int L = 12;
constexpr int B = 4, T = 2048, H = 16, D = 64;
constexpr int NPOS = B * T * H;                     // 131072 positions (b,t,h)
constexpr long long SLAYER = (long long)NPOS * D;   // elements per layer slice
constexpr int PW = 16;                              // positions per wave

typedef __attribute__((ext_vector_type(8))) short bf16x8;
typedef __attribute__((ext_vector_type(4))) float f32x4;

__device__ __forceinline__ short f2bf(float f) {
  union { __hip_bfloat16 h; short s; } u;
  u.h = __float2bfloat16(f);
  return u.s;
}

// MT[n][k] = M[k][n] = sum_e Wq[e][k] * Wk[e][n], stored bf16.
// (score_l = x^T M y_l; q = x^T M, computed as GEMM Q = X * M)
__global__ __launch_bounds__(64) void cla_precompute_MT(
    const float* __restrict__ Wq, const float* __restrict__ Wk,
    short* __restrict__ MT) {
  const int n = blockIdx.x;    // 64 blocks
  const int k = threadIdx.x;   // 64 threads
  float acc = 0.f;
  #pragma unroll
  for (int e = 0; e < D; ++e)
    acc = fmaf(Wq[e * D + k], Wk[e * D + n], acc);
  MT[n * D + k] = f2bf(acc);
}

// 16-lane-row sum via DPP row_ror — VALU pipe, every lane gets the row sum.
// (HW-verified in round 3's passing run.)
template <int CTRL>
__device__ __forceinline__ float ror_add(float x) {
  int moved = __builtin_amdgcn_update_dpp(0, __float_as_int(x), CTRL, 0xF, 0xF,
                                          false);
  return x + __int_as_float(moved);
}
__device__ __forceinline__ float row_sum16(float x) {
  x = ror_add<0x121>(x);  // row_ror:1
  x = ror_add<0x122>(x);  // row_ror:2
  x = ror_add<0x124>(x);  // row_ror:4
  x = ror_add<0x128>(x);  // row_ror:8
  return x;
}

__global__ __launch_bounds__(256, 3) void cla_main(
    const float* __restrict__ cur, const float* __restrict__ all,
    const short* __restrict__ MT, const float* __restrict__ scales,
    const float* __restrict__ temperature, float* __restrict__ out) {
  __shared__ float qlds[4][PW * D];   // per-wave q tile (16 KB / block)

  const int lane = threadIdx.x & 63;
  const int w    = threadIdx.x >> 6;
  const int wid  = blockIdx.x * 4 + w;
  const int pos0 = wid * PW;

  const int ncol = lane & 15;
  const int kq   = lane >> 4;

  // ---- Phase 1: q = X * M via MFMA (16 positions per wave) ----
  // B-frags: B[k][n] = MT[n][k]; lane holds k = kc*32 + kq*8 + j (contig-8).
  bf16x8 bm[4][2];
  #pragma unroll
  for (int nt = 0; nt < 4; ++nt)
    #pragma unroll
    for (int kc = 0; kc < 2; ++kc)
      bm[nt][kc] =
          *(const bf16x8*)(MT + (nt * 16 + ncol) * D + kc * 32 + kq * 8);

  f32x4 acc[4] = {};
  const float* xb = cur + (size_t)(pos0 + ncol) * D + kq * 8;
  #pragma unroll
  for (int kc = 0; kc < 2; ++kc) {
    const float4 xlo = *(const float4*)(xb + kc * 32);
    const float4 xhi = *(const float4*)(xb + kc * 32 + 4);
    short a8[8] = {f2bf(xlo.x), f2bf(xlo.y), f2bf(xlo.z), f2bf(xlo.w),
                   f2bf(xhi.x), f2bf(xhi.y), f2bf(xhi.z), f2bf(xhi.w)};
    bf16x8 af;
    __builtin_memcpy(&af, a8, 16);
    #pragma unroll
    for (int nt = 0; nt < 4; ++nt)
      acc[nt] = __builtin_amdgcn_mfma_f32_16x16x32_bf16(af, bm[nt][kc],
                                                        acc[nt], 0, 0, 0);
  }

  const float inv_scale = 1.0f / (8.0f * fabsf(temperature[0]));  // sqrt(64)=8

  // C layout: row(pos) = 4*kq + r, col(n) = nt*16 + ncol. Fold inv_scale in.
  #pragma unroll
  for (int nt = 0; nt < 4; ++nt)
    #pragma unroll
    for (int r = 0; r < 4; ++r)
      qlds[w][(4 * kq + r) * D + nt * 16 + ncol] = acc[nt][r] * inv_scale;
  // same-wave LDS write->read; compiler inserts lgkmcnt, no barrier needed.

  float scl[L];
  #pragma unroll
  for (int l = 0; l < L; ++l) scl[l] = scales[l];

  // ---- Phase 2: stream all_layers (4 positions per iteration) ----
  const int g = lane >> 4;   // position group within wave
  const int j = lane & 15;   // float4 chunk within position

  for (int it = 0; it < 4; ++it) {
    const size_t base = (size_t)(pos0 + it * 4) * D + (size_t)lane * 4;
    const float4 q = *(const float4*)&qlds[w][(it * 4 + g) * D + 4 * j];

    float4 y[L];
    #pragma unroll
    for (int l = 0; l < L; ++l)
      y[l] = *(const float4*)(all + (size_t)l * SLAYER + base);

    float sc[L];
    #pragma unroll
    for (int l = 0; l < L; ++l) {
      float s = q.x * y[l].x + q.y * y[l].y + q.z * y[l].z + q.w * y[l].w;
      sc[l] = row_sum16(s);   // inv_scale already folded into q
    }

    float mx = sc[0];
    #pragma unroll
    for (int l = 1; l < L; ++l) mx = fmaxf(mx, sc[l]);
    float sum = 0.f;
    #pragma unroll
    for (int l = 0; l < L; ++l) { sc[l] = __expf(sc[l] - mx); sum += sc[l]; }
    const float inv_sum = 1.0f / sum;

    float wgt[L];
    float ssum = 0.f;
    #pragma unroll
    for (int l = 0; l < L; ++l) {
      wgt[l] = sc[l] * inv_sum * scl[l];
      ssum += wgt[l];
    }
    const float r = 1.0f / (ssum + 1e-6f);

    float o0 = 0.f, o1 = 0.f, o2 = 0.f, o3 = 0.f;
    #pragma unroll
    for (int l = 0; l < L; ++l) {
      const float wl = wgt[l] * r * scl[l];
      o0 = fmaf(wl, y[l].x, o0);
      o1 = fmaf(wl, y[l].y, o1);
      o2 = fmaf(wl, y[l].z, o2);
      o3 = fmaf(wl, y[l].w, o3);
    }
    *(float4*)(out + base) = make_float4(o0, o1, o2, o3);
  }
}

extern "C" void kernel_launch(void* const* d_in, const int* in_sizes, int n_in,
                              void* d_out, int out_size, void* d_ws, size_t ws_size,
                              hipStream_t stream) {
  const float* cur    = (const float*)d_in[0];
  const float* all    = (const float*)d_in[1];
  const float* Wq     = (const float*)d_in[2];
  const float* Wk     = (const float*)d_in[3];
  const float* scales = (const float*)d_in[4];
  const float* temp   = (const float*)d_in[5];
  short* MT = (short*)d_ws;   // 8 KB scratch: (Wq^T Wk)^T in bf16

  cla_precompute_MT<<<64, 64, 0, stream>>>(Wq, Wk, MT);

  const int nwaves  = NPOS / PW;    // 8192 waves
  const int nblocks = nwaves / 4;   // 2048 blocks of 256 threads
  cla_main<<<nblocks, 256, 0, stream>>>(cur, all, MT, scales, temp,
                                        (float*)d_out);
}